// Round 8
// baseline (158.334 us; speedup 1.0000x reference)
//
#include <hip/hip_runtime.h>

#define N_STFT 1025
#define N_MELS 128
#define BATCH 4
#define TIME 1024
#define MAX_ITER 20

typedef unsigned long long u64;
typedef unsigned int u32;

// Extract per-frequency sparse filterbank structure: each fb row f has at most
// 2 nonzeros at adjacent mel indices (m0, m0+1) — triangular filters.
__global__ void imel_prep(const float* __restrict__ fb, int* __restrict__ m0f,
                          float* __restrict__ w0a, float* __restrict__ w1a) {
  const int w = threadIdx.x >> 6, l = threadIdx.x & 63;
  const int f = blockIdx.x * 4 + w;
  if (f >= N_STFT) return;
  const float* row = fb + (size_t)f * N_MELS;
  const unsigned long long mlo = __ballot(row[l] != 0.0f);
  const unsigned long long mhi = __ballot(row[l + 64] != 0.0f);
  if (l == 0) {
    int m0 = mlo ? __builtin_ctzll(mlo)
                 : (mhi ? 64 + __builtin_ctzll(mhi) : 0);
    if (m0 > N_MELS - 2) m0 = N_MELS - 2;   // all-zero rows (f=0, f=1024) -> w=0
    m0f[f] = m0;
    w0a[f] = row[m0];
    w1a[f] = row[m0 + 1];
  }
}

// pack two rounded fixed-point values into one u64 (no inter-half carry:
// both halves are >=0 and stay < 2^31 during accumulation)
__device__ __forceinline__ u64 pk_rn(float x, float y) {
  return (u64)(u32)__float2int_rn(x) | ((u64)(u32)__float2int_rn(y) << 32);
}

// 256-thread blocks (4 waves) handle ONE packed row-pair; wave q owns freq
// quarter (lane = 4 contiguous bins). 2048 blocks -> 8 blocks/CU = 32 waves/CU
// with 8 independent barrier groups (phase decorrelation).
//
// Round-7 lesson: LDS cost = bank traffic, not instruction count; both pipes
// sat at ~50% under the 2-barrier/diff-phase structure. This version removes
// the diff materialization: rm[k] is loop-invariant, so GRAD_C*mel folds into
// per-lane constants (cc, rwg) and backward reads P directly:
//   g = Pf0*rwg0 + Pf1*rwg1 + cc     (== old  d0*rw0 + d1*rw1)
// P is ping-ponged (zero other-parity buffer during gather phase; loop
// unrolled x2 so all LDS addresses stay static). Grid is XCD-swizzled so
// t-adjacent pairs share an XCD L2 and 8 B output granules merge.
__global__ __launch_bounds__(256, 8) void imel_main(
    const float* __restrict__ melspec, const float* __restrict__ spec_init,
    const int* __restrict__ m0f, const float* __restrict__ w0a,
    const float* __restrict__ w1a, float* __restrict__ out) {
  __shared__ u64   s_P[2][N_MELS];   // ping-pong packed fixed-point (i32x2)
  __shared__ float s_out[2][1060];   // swizzle-padded: idx = f + (f>>5)

  const int tid = threadIdx.x;
  const int q   = tid >> 6;        // wave 0..3 = freq quarter
  const int l   = tid & 63;
  const int c   = q * 64 + l;      // chunk 0..255 (4 freqs each)
  // XCD-contiguous swizzle: blocks on one XCD cover a contiguous t-range
  const int flat = (blockIdx.x & 7) * 256 + (blockIdx.x >> 3);
  const int b   = flat >> 9;       // 512 row-pairs per batch
  const int t0  = (flat & 511) << 1;  // rows t0 (A), t0+1 (B)

  const float SCALE = 16777216.0f;            // 2^24 fixed point
  const float INV_SCALE = 1.0f / 16777216.0f;
  const float GRAD_C = (-2.0f / (BATCH * TIME)) * INV_SCALE;
  const float NC2 = -GRAD_C * INV_SCALE;

  // per-lane static structure, f = 4c + k
  float rsA[4], rsB[4], rbA[4], rbB[4];
  float rw0[4], rw1[4];            // scatter weights, pre-scaled by 2^24
  float rwg0[4], rwg1[4];          // gather weights: NC2 * rw
  float ccA[4], ccB[4];            // folded mel targets per (k, row)
  int rm[4];

  const float* srowA = spec_init + (size_t)(b * TIME + t0) * N_STFT;
  const float* srowB = srowA + N_STFT;
  const float* melb  = melspec + (size_t)b * N_MELS * TIME + t0;
#pragma unroll
  for (int k = 0; k < 4; ++k) {
    const int f = (c << 2) + k;
    rsA[k] = srowA[f];
    rsB[k] = srowB[f];
    rm[k]  = m0f[f];
    rw0[k] = w0a[f] * SCALE;
    rw1[k] = w1a[f] * SCALE;
    rwg0[k] = NC2 * rw0[k];
    rwg1[k] = NC2 * rw1[k];
    // cc = GRAD_C*(mel[rm]*rw0 + mel[rm+1]*rw1), per row
    const float m0A = melb[(size_t)rm[k] * TIME];
    const float m1A = melb[(size_t)(rm[k] + 1) * TIME];
    const float m0B = melb[(size_t)rm[k] * TIME + 1];
    const float m1B = melb[(size_t)(rm[k] + 1) * TIME + 1];
    ccA[k] = GRAD_C * fmaf(m0A, rw0[k], m1A * rw1[k]);
    ccB[k] = GRAD_C * fmaf(m0B, rw0[k], m1B * rw1[k]);
    rbA[k] = 0.f;
    rbB[k] = 0.f;
  }
  const bool tail = (c == 255);
  const float rtA = tail ? srowA[1024] : 0.f;  // f=1024: zero fb row -> copy
  const float rtB = tail ? srowB[1024] : 0.f;

  // loop-invariant advance flags (wave masks in SGPR pairs)
  const bool adv1 = (rm[1] != rm[0]);
  const bool adv2 = (rm[2] != rm[1]);
  const bool adv3 = (rm[3] != rm[2]);

  if (tid < N_MELS) s_P[0][tid] = 0ULL;
  __syncthreads();

  // one optimization step: scatter into Pc, gather from Pc, zero Po
  auto step = [&](u64* __restrict__ Pc, u64* __restrict__ Po) {
    // ---- forward: run-compacted packed scatter (ds_add_u64) ----
    {
      float a0A = rsA[0] * rw0[0], a1A = rsA[0] * rw1[0];
      float a0B = rsB[0] * rw0[0], a1B = rsB[0] * rw1[0];
      if (adv1) atomicAdd(&Pc[rm[0]], pk_rn(a0A, a0B));
      a0A = (adv1 ? a1A : a0A) + rsA[1] * rw0[1];
      a1A = (adv1 ? 0.f : a1A) + rsA[1] * rw1[1];
      a0B = (adv1 ? a1B : a0B) + rsB[1] * rw0[1];
      a1B = (adv1 ? 0.f : a1B) + rsB[1] * rw1[1];
      if (adv2) atomicAdd(&Pc[rm[1]], pk_rn(a0A, a0B));
      a0A = (adv2 ? a1A : a0A) + rsA[2] * rw0[2];
      a1A = (adv2 ? 0.f : a1A) + rsA[2] * rw1[2];
      a0B = (adv2 ? a1B : a0B) + rsB[2] * rw0[2];
      a1B = (adv2 ? 0.f : a1B) + rsB[2] * rw1[2];
      if (adv3) atomicAdd(&Pc[rm[2]], pk_rn(a0A, a0B));
      a0A = (adv3 ? a1A : a0A) + rsA[3] * rw0[3];
      a1A = (adv3 ? 0.f : a1A) + rsA[3] * rw1[3];
      a0B = (adv3 ? a1B : a0B) + rsB[3] * rw0[3];
      a1B = (adv3 ? 0.f : a1B) + rsB[3] * rw1[3];
      atomicAdd(&Pc[rm[3]],     pk_rn(a0A, a0B));
      atomicAdd(&Pc[rm[3] + 1], pk_rn(a1A, a1B));
    }
    __syncthreads();
    // ---- backward: read P directly (ds_read2_b64), folded constants ----
#pragma unroll
    for (int k = 0; k < 4; ++k) {
      const u64 wd0 = Pc[rm[k]];          // merges to ds_read2_b64
      const u64 wd1 = Pc[rm[k] + 1];
      const float p0A = (float)(int)(u32)wd0;
      const float p0B = (float)(int)(u32)(wd0 >> 32);
      const float p1A = (float)(int)(u32)wd1;
      const float p1B = (float)(int)(u32)(wd1 >> 32);
      const float gA = fmaf(p0A, rwg0[k], fmaf(p1A, rwg1[k], ccA[k]));
      const float gB = fmaf(p0B, rwg0[k], fmaf(p1B, rwg1[k], ccB[k]));
      rbA[k] = fmaf(0.9f, rbA[k], gA);
      rbB[k] = fmaf(0.9f, rbB[k], gB);
      rsA[k] = fmaxf(fmaf(-0.3f, rbA[k], rsA[k]), 0.f);
      rsB[k] = fmaxf(fmaf(-0.3f, rbB[k], rsB[k]), 0.f);
    }
    // zero the other-parity buffer for iter+1 (its readers finished before
    // this iteration's post-scatter barrier; next scatter is gated below)
    if (tid < N_MELS) Po[tid] = 0ULL;
    __syncthreads();
  };

  for (int it2 = 0; it2 < MAX_ITER / 2; ++it2) {
    step(s_P[0], s_P[1]);   // static LDS addresses in both bodies
    step(s_P[1], s_P[0]);
  }

  // ---- epilogue: transpose (f-major regs) -> (B, F, T) via swizzled LDS ----
#pragma unroll
  for (int k = 0; k < 4; ++k) {
    const int f = (c << 2) + k;
    s_out[0][f + (f >> 5)] = rsA[k];
    s_out[1][f + (f >> 5)] = rsB[k];
  }
  if (tail) {
    s_out[0][1056] = rtA;    // f=1024 -> 1024 + (1024>>5)
    s_out[1][1056] = rtB;
  }
  __syncthreads();

  const int tl = tid & 1;    // t offset within the block's 2 rows
  const int fg = tid >> 1;   // 128 f phases
  float* obase = out + (size_t)b * N_STFT * TIME + t0 + tl;
  for (int f = fg; f < N_STFT; f += 128) {
    obase[(size_t)f * TIME] = s_out[tl][f + (f >> 5)];
  }
}

extern "C" void kernel_launch(void* const* d_in, const int* in_sizes, int n_in,
                              void* d_out, int out_size, void* d_ws, size_t ws_size,
                              hipStream_t stream) {
  const float* melspec = (const float*)d_in[0];
  const float* spec_init = (const float*)d_in[1];
  const float* fb = (const float*)d_in[2];
  float* out = (float*)d_out;

  int* m0f = (int*)d_ws;                          // 1025 ints
  float* w0a = (float*)((char*)d_ws + 5120);      // 1025 floats
  float* w1a = (float*)((char*)d_ws + 10240);     // 1025 floats

  imel_prep<<<dim3(257), dim3(256), 0, stream>>>(fb, m0f, w0a, w1a);
  imel_main<<<dim3(2048), dim3(256), 0, stream>>>(melspec, spec_init, m0f, w0a, w1a, out);
}

// Round 9
// 133.838 us; speedup vs baseline: 1.1830x; 1.1830x over previous
//
#include <hip/hip_runtime.h>

#define N_STFT 1025
#define N_MELS 128
#define BATCH 4
#define TIME 1024
#define MAX_ITER 20

typedef unsigned int u32;

// Extract per-frequency sparse filterbank structure: each fb row f has at most
// 2 nonzeros at adjacent mel indices (m0, m0+1) — triangular filters.
__global__ void imel_prep(const float* __restrict__ fb, int* __restrict__ m0f,
                          float* __restrict__ w0a, float* __restrict__ w1a) {
  const int w = threadIdx.x >> 6, l = threadIdx.x & 63;
  const int f = blockIdx.x * 4 + w;
  if (f >= N_STFT) return;
  const float* row = fb + (size_t)f * N_MELS;
  const unsigned long long mlo = __ballot(row[l] != 0.0f);
  const unsigned long long mhi = __ballot(row[l + 64] != 0.0f);
  if (l == 0) {
    int m0 = mlo ? __builtin_ctzll(mlo)
                 : (mhi ? 64 + __builtin_ctzll(mhi) : 0);
    if (m0 > N_MELS - 2) m0 = N_MELS - 2;   // all-zero rows (f=0, f=1024) -> w=0
    m0f[f] = m0;
    w0a[f] = row[m0];
    w1a[f] = row[m0 + 1];
  }
}

// One WAVE owns one full (b,t) row: 64 lanes x 16 bins = bins 0..1023 (f=1024
// is a zero fb row -> passthrough). P[128] is WAVE-PRIVATE in LDS, so the
// scatter -> gather -> zero cycle is wave-synchronous: same-wave DS ops
// execute in program order through the DS pipe -> NO __syncthreads in the hot
// loop (rounds 6-8 showed the 2-barrier phase structure was the ~52us floor;
// both pipes idled at phase edges).
// 256-thread blocks = 4 rows; __launch_bounds__(256,4) = 128-VGPR budget for
// the ~110-reg per-lane state (round 4's spill was at the 64-reg budget).
// Diff phase is folded away (round 8): g = C2*(Pf0*rw0 + Pf1*rw1) + cc, with
// cc = -2/(B*T)*(mel[rm]*w0 + mel[rm+1]*w1) per lane-bin (mel staged through
// LDS coalescedly — round 8's scattered mel reads cost 19 MB of overfetch).
__global__ __launch_bounds__(256, 4) void imel_main(
    const float* __restrict__ melspec, const float* __restrict__ spec_init,
    const int* __restrict__ m0f, const float* __restrict__ w0a,
    const float* __restrict__ w1a, float* __restrict__ out) {
  __shared__ u32   s_P[4][N_MELS];   // wave-private fixed-point 2^24 accum
  __shared__ float s_mel[4][N_MELS]; // staged mel column per row (prologue)
  __shared__ float s_out[4][1060];   // swizzle-padded: idx = f + (f>>5)

  const int tid = threadIdx.x;
  const int w   = tid >> 6;        // wave 0..3 = local row
  const int l   = tid & 63;
  const int blk = blockIdx.x;
  const int b   = blk >> 8;
  const int t0  = (blk & 255) << 2;
  const int t   = t0 + w;

  // ---- stage mel columns coalescedly: s_mel[r][m] = mel[b][m][t0+r] ----
  for (int i = tid; i < 4 * N_MELS; i += 256) {
    const int m = i >> 2, r = i & 3;
    s_mel[r][m] = melspec[((size_t)b * N_MELS + m) * TIME + t0 + r];
  }
  __syncthreads();

  const float SCALE  = 16777216.0f;                  // 2^24
  const float GRAD_N = -2.0f / (BATCH * TIME);       // true grad prefactor
  // C2 = +2/(B*T) * 2^-48  (rw* carry 2^24 each)
  const float C2 = (2.0f / (BATCH * TIME)) * 3.5527136788e-15f;

  // per-lane static structure, f = 16*l + k
  float rs[16], rb[16], rw0[16], rw1[16], cc[16];
  int rm[16];

  const float* srow = spec_init + (size_t)(b * TIME + t) * N_STFT;
#pragma unroll
  for (int k = 0; k < 16; ++k) {
    const int f = (l << 4) + k;
    rs[k] = srow[f];
    const int m = m0f[f];
    rm[k] = m;
    const float w0 = w0a[f], w1 = w1a[f];
    rw0[k] = w0 * SCALE;
    rw1[k] = w1 * SCALE;
    cc[k]  = GRAD_N * fmaf(s_mel[w][m], w0, s_mel[w][m + 1] * w1);
    rb[k]  = 0.f;
  }
  const float rtail = (l == 63) ? srow[1024] : 0.f;  // f=1024: zero fb row

  // loop-invariant advance flags (m0 monotone, step <= 1 per bin)
  bool adv[16];
  adv[0] = false;
#pragma unroll
  for (int k = 1; k < 16; ++k) adv[k] = (rm[k] != rm[k - 1]);

  u32* __restrict__ Pw = &s_P[w][0];
  Pw[l] = 0u;
  Pw[l + 64] = 0u;
  // wave-private: no barrier needed anywhere in the hot loop

  for (int it = 0; it < MAX_ITER; ++it) {
    // ---- forward: run-compacted fixed-point scatter (ds_add_u32) ----
    {
      float a0 = rs[0] * rw0[0];
      float a1 = rs[0] * rw1[0];
#pragma unroll
      for (int k = 1; k < 16; ++k) {
        if (adv[k]) atomicAdd(&Pw[rm[k - 1]], (u32)__float2int_rn(a0));
        const float n0 = (adv[k] ? a1 : a0) + rs[k] * rw0[k];
        a1 = (adv[k] ? 0.f : a1) + rs[k] * rw1[k];
        a0 = n0;
      }
      atomicAdd(&Pw[rm[15]],     (u32)__float2int_rn(a0));
      atomicAdd(&Pw[rm[15] + 1], (u32)__float2int_rn(a1));
    }
    __builtin_amdgcn_wave_barrier();   // scheduling fence (no hw cost)
    // ---- backward: compacted gather (fresh read only on advance; all
    //      addresses static -> reads pipeline), momentum, clamp ----
    {
      float p0 = (float)(int)Pw[rm[0]];
      float p1 = (float)(int)Pw[rm[0] + 1];
#pragma unroll
      for (int k = 0; k < 16; ++k) {
        if (k > 0 && adv[k]) {
          p0 = p1;
          p1 = (float)(int)Pw[rm[k] + 1];
        }
        const float h = fmaf(p1, rw1[k], p0 * rw0[k]);
        const float g = fmaf(h, C2, cc[k]);      // == -inv*(diff . w)
        rb[k] = fmaf(0.9f, rb[k], g);
        rs[k] = fmaxf(fmaf(-0.3f, rb[k], rs[k]), 0.f);
      }
    }
    __builtin_amdgcn_wave_barrier();
    // ---- zero P for next iteration (wave-private, ordered by DS pipe) ----
    Pw[l] = 0u;
    Pw[l + 64] = 0u;
    __builtin_amdgcn_wave_barrier();
  }

  // ---- epilogue: transpose (f-major regs) -> (B, F, T) via swizzled LDS ----
#pragma unroll
  for (int k = 0; k < 16; ++k) {
    const int f = (l << 4) + k;
    s_out[w][f + (f >> 5)] = rs[k];
  }
  if (l == 63) s_out[w][1056] = rtail;   // f=1024 -> 1024 + (1024>>5)
  __syncthreads();

  const int tl = tid & 3;    // t offset within the block's 4 rows
  const int fg = tid >> 2;   // 64 f phases
  float* obase = out + (size_t)b * N_STFT * TIME + t0 + tl;
  for (int f = fg; f < N_STFT; f += 64) {
    obase[(size_t)f * TIME] = s_out[tl][f + (f >> 5)];
  }
}

extern "C" void kernel_launch(void* const* d_in, const int* in_sizes, int n_in,
                              void* d_out, int out_size, void* d_ws, size_t ws_size,
                              hipStream_t stream) {
  const float* melspec = (const float*)d_in[0];
  const float* spec_init = (const float*)d_in[1];
  const float* fb = (const float*)d_in[2];
  float* out = (float*)d_out;

  int* m0f = (int*)d_ws;                          // 1025 ints
  float* w0a = (float*)((char*)d_ws + 5120);      // 1025 floats
  float* w1a = (float*)((char*)d_ws + 10240);     // 1025 floats

  imel_prep<<<dim3(257), dim3(256), 0, stream>>>(fb, m0f, w0a, w1a);
  imel_main<<<dim3(1024), dim3(256), 0, stream>>>(melspec, spec_init, m0f, w0a, w1a, out);
}

// Round 10
// 116.336 us; speedup vs baseline: 1.3610x; 1.1504x over previous
//
#include <hip/hip_runtime.h>

#define N_STFT 1025
#define N_MELS 128
#define BATCH 4
#define TIME 1024
#define MAX_ITER 20

typedef unsigned long long u64;
typedef unsigned int u32;

// Extract per-frequency sparse filterbank structure: each fb row f has at most
// 2 nonzeros at adjacent mel indices (m0, m0+1) — triangular filters.
__global__ void imel_prep(const float* __restrict__ fb, int* __restrict__ m0f,
                          float* __restrict__ w0a, float* __restrict__ w1a) {
  const int w = threadIdx.x >> 6, l = threadIdx.x & 63;
  const int f = blockIdx.x * 4 + w;
  if (f >= N_STFT) return;
  const float* row = fb + (size_t)f * N_MELS;
  const unsigned long long mlo = __ballot(row[l] != 0.0f);
  const unsigned long long mhi = __ballot(row[l + 64] != 0.0f);
  if (l == 0) {
    int m0 = mlo ? __builtin_ctzll(mlo)
                 : (mhi ? 64 + __builtin_ctzll(mhi) : 0);
    if (m0 > N_MELS - 2) m0 = N_MELS - 2;   // all-zero rows (f=0, f=1024) -> w=0
    m0f[f] = m0;
    w0a[f] = row[m0];
    w1a[f] = row[m0 + 1];
  }
}

// pack two rounded fixed-point values into one u64 (no inter-half carry:
// both halves are >=0 and stay < 2^31 during accumulation)
__device__ __forceinline__ u64 pk_rn(float x, float y) {
  return (u64)(u32)__float2int_rn(x) | ((u64)(u32)__float2int_rn(y) << 32);
}

// One WAVE owns TWO full (b,t) rows: 64 lanes x 16 bins, P[128] packed as
// u64 {rowA, rowB} and WAVE-PRIVATE in LDS -> zero __syncthreads in the hot
// loop (r6-r8: the 2-barrier phase structure was the ~52us floor) AND ~2x
// fewer DS issue slots per row than r9 (predicated DS ops issue for the whole
// wave, so issue count = k-loop length; packing 2 rows amortizes it).
// Gather reads BOTH mels per k unconditionally (ds_read2_b64): same issue
// count as the predicated version but no serial select chain.
// State ~170 VGPR -> __launch_bounds__(256,2) gives the 256-reg budget (r9's
// (256,4)=128 budget made the allocator pick 64 regs and spill).
// Diff phase folded away (r8): g = C2*(P0*rw0 + P1*rw1) + cc.
__global__ __launch_bounds__(256, 2) void imel_main(
    const float* __restrict__ melspec, const float* __restrict__ spec_init,
    const int* __restrict__ m0f, const float* __restrict__ w0a,
    const float* __restrict__ w1a, float* __restrict__ out) {
  __shared__ u64   s_P[4][N_MELS];   // per-wave private, 2 rows packed
  __shared__ float s_mel[8][N_MELS]; // staged mel columns (prologue only)
  __shared__ float s_out[8][1060];   // swizzle-padded: idx = f + (f>>5)

  const int tid = threadIdx.x;
  const int w   = tid >> 6;        // wave 0..3 -> rows t0+2w, t0+2w+1
  const int l   = tid & 63;
  // XCD swizzle: each XCD covers a contiguous (b,t) range -> melspec slice
  // per XCD ~0.5 MB (L2-resident) and adjacent output granules merge
  const int flat = (blockIdx.x & 7) * 64 + (blockIdx.x >> 3);
  const int b   = flat >> 7;          // 128 flats per batch
  const int t0  = (flat & 127) << 3;  // block covers t0..t0+7
  const int tA  = t0 + 2 * w;

  // ---- stage mel columns coalescedly: s_mel[r][m] = mel[b][m][t0+r] ----
  for (int i = tid; i < 8 * N_MELS; i += 256) {
    const int m = i >> 3, r = i & 7;
    s_mel[r][m] = melspec[((size_t)b * N_MELS + m) * TIME + t0 + r];
  }
  __syncthreads();

  const float SCALE  = 16777216.0f;              // 2^24 fixed point
  const float GRAD_N = -2.0f / (BATCH * TIME);   // true grad prefactor
  const float C2 = (2.0f / (BATCH * TIME)) * 3.5527136788005009e-15f; // *2^-48

  // per-lane static structure, f = 16*l + k  (f=1024: zero fb row -> copy)
  float rsA[16], rsB[16], rbA[16], rbB[16];
  float rw0[16], rw1[16], ccA[16], ccB[16];
  int rm[16];

  const float* srowA = spec_init + (size_t)(b * TIME + tA) * N_STFT;
  const float* srowB = srowA + N_STFT;
  const float* melA = &s_mel[2 * w][0];
  const float* melB = &s_mel[2 * w + 1][0];
#pragma unroll
  for (int k = 0; k < 16; ++k) {
    const int f = (l << 4) + k;
    rsA[k] = srowA[f];
    rsB[k] = srowB[f];
    const int m = m0f[f];
    rm[k] = m;
    const float w0 = w0a[f], w1 = w1a[f];
    rw0[k] = w0 * SCALE;
    rw1[k] = w1 * SCALE;
    ccA[k] = GRAD_N * fmaf(melA[m], w0, melA[m + 1] * w1);
    ccB[k] = GRAD_N * fmaf(melB[m], w0, melB[m + 1] * w1);
    rbA[k] = 0.f;
    rbB[k] = 0.f;
  }
  const float rtA = (l == 63) ? srowA[1024] : 0.f;
  const float rtB = (l == 63) ? srowB[1024] : 0.f;

  // loop-invariant advance flags (m0 monotone, step <= 1 per bin)
  bool adv[16];
  adv[0] = false;
#pragma unroll
  for (int k = 1; k < 16; ++k) adv[k] = (rm[k] != rm[k - 1]);

  u64* __restrict__ Pw = &s_P[w][0];
  Pw[l] = 0ULL;
  Pw[l + 64] = 0ULL;
  // wave-private P: no block barrier anywhere in the hot loop

  for (int it = 0; it < MAX_ITER; ++it) {
    // ---- forward: run-compacted packed scatter (ds_add_u64) ----
    {
      float a0A = rsA[0] * rw0[0], a1A = rsA[0] * rw1[0];
      float a0B = rsB[0] * rw0[0], a1B = rsB[0] * rw1[0];
#pragma unroll
      for (int k = 1; k < 16; ++k) {
        if (adv[k]) atomicAdd(&Pw[rm[k - 1]], pk_rn(a0A, a0B));
        const float n0A = (adv[k] ? a1A : a0A) + rsA[k] * rw0[k];
        a1A = (adv[k] ? 0.f : a1A) + rsA[k] * rw1[k];
        a0A = n0A;
        const float n0B = (adv[k] ? a1B : a0B) + rsB[k] * rw0[k];
        a1B = (adv[k] ? 0.f : a1B) + rsB[k] * rw1[k];
        a0B = n0B;
      }
      atomicAdd(&Pw[rm[15]],     pk_rn(a0A, a0B));
      atomicAdd(&Pw[rm[15] + 1], pk_rn(a1A, a1B));
    }
    __builtin_amdgcn_wave_barrier();   // scheduling fence only
    // ---- backward: unconditional ds_read2_b64 per k (no select chain),
    //      momentum + clamp, all k independent ----
#pragma unroll
    for (int k = 0; k < 16; ++k) {
      const u64 q0 = Pw[rm[k]];        // pairs into ds_read2_b64
      const u64 q1 = Pw[rm[k] + 1];
      const float p0A = (float)(int)(u32)q0;
      const float p0B = (float)(int)(u32)(q0 >> 32);
      const float p1A = (float)(int)(u32)q1;
      const float p1B = (float)(int)(u32)(q1 >> 32);
      const float gA = fmaf(fmaf(p1A, rw1[k], p0A * rw0[k]), C2, ccA[k]);
      const float gB = fmaf(fmaf(p1B, rw1[k], p0B * rw0[k]), C2, ccB[k]);
      rbA[k] = fmaf(0.9f, rbA[k], gA);
      rbB[k] = fmaf(0.9f, rbB[k], gB);
      rsA[k] = fmaxf(fmaf(-0.3f, rbA[k], rsA[k]), 0.f);
      rsB[k] = fmaxf(fmaf(-0.3f, rbB[k], rsB[k]), 0.f);
    }
    __builtin_amdgcn_wave_barrier();
    // ---- zero P for next iteration (same-wave DS program order) ----
    Pw[l] = 0ULL;
    Pw[l + 64] = 0ULL;
    __builtin_amdgcn_wave_barrier();
  }

  // ---- epilogue: transpose (f-major regs) -> (B, F, T) via swizzled LDS ----
#pragma unroll
  for (int k = 0; k < 16; ++k) {
    const int f = (l << 4) + k;
    s_out[2 * w][f + (f >> 5)]     = rsA[k];
    s_out[2 * w + 1][f + (f >> 5)] = rsB[k];
  }
  if (l == 63) {
    s_out[2 * w][1056]     = rtA;    // f=1024 -> 1024 + (1024>>5)
    s_out[2 * w + 1][1056] = rtB;
  }
  __syncthreads();

  const int tl = tid & 7;    // t offset within the block's 8 rows
  const int fg = tid >> 3;   // 32 f phases
  float* obase = out + (size_t)b * N_STFT * TIME + t0 + tl;
  for (int f = fg; f < N_STFT; f += 32) {
    obase[(size_t)f * TIME] = s_out[tl][f + (f >> 5)];
  }
}

extern "C" void kernel_launch(void* const* d_in, const int* in_sizes, int n_in,
                              void* d_out, int out_size, void* d_ws, size_t ws_size,
                              hipStream_t stream) {
  const float* melspec = (const float*)d_in[0];
  const float* spec_init = (const float*)d_in[1];
  const float* fb = (const float*)d_in[2];
  float* out = (float*)d_out;

  int* m0f = (int*)d_ws;                          // 1025 ints
  float* w0a = (float*)((char*)d_ws + 5120);      // 1025 floats
  float* w1a = (float*)((char*)d_ws + 10240);     // 1025 floats

  imel_prep<<<dim3(257), dim3(256), 0, stream>>>(fb, m0f, w0a, w1a);
  imel_main<<<dim3(512), dim3(256), 0, stream>>>(melspec, spec_init, m0f, w0a, w1a, out);
}